// Round 5
// baseline (185.116 us; speedup 1.0000x reference)
//
#include <hip/hip_runtime.h>

#define B_ 4
#define C_ 16
#define H_ 64
#define W_ 64
#define F_ 32

// 2 px/thread (vertical row pair) x 8 channels/thread (2-way channel split).
// Block 256 = 64 cols x {2 channel halves} x {2 row pairs} -> 4 rows x 64 cols, one f.
// Grid = B*16*F = 2048 blocks -> 8192 waves -> 8 waves/SIMD (max occupancy),
// with R4's instruction density (12 loads feeding 18 evals per channel).
__global__ __launch_bounds__(256, 8)
void ka_rconv_kernel(const float* __restrict__ xin,
                     const float* __restrict__ nums,
                     const float* __restrict__ denoms,
                     float* __restrict__ out) {
    __shared__ float red[2 * 2 * 64];   // [rp][row-in-pair][col], stride-4B -> conflict-free

    const int tid = threadIdx.x;
    const int col = tid & 63;          // lane = column -> coalesced
    const int g   = (tid >> 6) & 1;    // channel half (0: c0..7, 1: c8..15)
    const int rp  = tid >> 7;          // row pair within the 4-row tile

    int bid = blockIdx.x;
    const int f  = bid & 31;  bid >>= 5;
    const int t4 = bid & 15;  bid >>= 4;   // 4-row tile
    const int b  = bid;
    const int gy0 = t4 * 4 + rp * 2;       // first of this thread's 2 rows

    // 12 clamped offsets (rows gy0-1..gy0+2, cols col-1..col+1) + float 0/1 masks.
    // Row validity is wave-uniform (rp uniform per wave) -> compiler scalarizes it.
    int   off[4][3];
    float msk[4][3];
    #pragma unroll
    for (int a = 0; a < 4; ++a) {
        const int gy   = gy0 + a - 1;
        const bool vy  = (gy >= 0) && (gy < H_);
        const int gyc  = min(max(gy, 0), H_ - 1);
        #pragma unroll
        for (int j = 0; j < 3; ++j) {
            const int gx  = col + j - 1;
            const bool vx = (gx >= 0) && (gx < W_);
            const int gxc = min(max(gx, 0), W_ - 1);
            off[a][j] = gyc * W_ + gxc;
            msk[a][j] = (vy && vx) ? 1.0f : 0.0f;   // zero-pad: padded tap contributes n0/1
        }
    }

    const int c0 = g * 8;
    const float* nbase = nums   + ((size_t)f * C_ + c0) * 54;   // uniform -> s_load
    const float* dbase = denoms + ((size_t)f * C_ + c0) * 36;
    const float* xb    = xin + ((size_t)b * C_ + c0) * (H_ * W_);

    float acc0 = 0.f, acc1 = 0.f;

    for (int c = 0; c < 8; ++c) {
        const float* xc = xb + c * (H_ * W_);
        float xv[4][3];
        #pragma unroll
        for (int a = 0; a < 4; ++a)
            #pragma unroll
            for (int j = 0; j < 3; ++j)
                xv[a][j] = xc[off[a][j]] * msk[a][j];   // clamped load, mask-mul to zero

        const float* np = nbase + c * 54;
        const float* dp = dbase + c * 36;
        #pragma unroll
        for (int a = 0; a < 3; ++a) {
            #pragma unroll
            for (int j = 0; j < 3; ++j) {
                const int t = a * 3 + j;
                const float n0 = np[t*6+0], n1 = np[t*6+1], n2 = np[t*6+2];
                const float n3 = np[t*6+3], n4 = np[t*6+4], n5 = np[t*6+5];
                const float d0 = dp[t*4+0], d1 = dp[t*4+1], d2 = dp[t*4+2], d3 = dp[t*4+3];

                const float x0 = xv[a][j];       // row gy0
                const float x1 = xv[a + 1][j];   // row gy0+1

                float P0 = fmaf(n5, x0, n4);
                float P1 = fmaf(n5, x1, n4);
                P0 = fmaf(P0, x0, n3);  P1 = fmaf(P1, x1, n3);
                P0 = fmaf(P0, x0, n2);  P1 = fmaf(P1, x1, n2);
                P0 = fmaf(P0, x0, n1);  P1 = fmaf(P1, x1, n1);
                P0 = fmaf(P0, x0, n0);  P1 = fmaf(P1, x1, n0);

                float Q0 = fmaf(d3, x0, d2);
                float Q1 = fmaf(d3, x1, d2);
                Q0 = fmaf(Q0, x0, d1);  Q1 = fmaf(Q1, x1, d1);
                Q0 = fmaf(Q0, x0, d0);  Q1 = fmaf(Q1, x1, d0);
                Q0 *= x0;               Q1 *= x1;
                Q0 = 1.0f + fabsf(Q0);  Q1 = 1.0f + fabsf(Q1);

                acc0 = fmaf(P0, __builtin_amdgcn_rcpf(Q0), acc0);
                acc1 = fmaf(P1, __builtin_amdgcn_rcpf(Q1), acc1);
            }
        }
    }

    // 2-way channel reduction through LDS, then store (wave-uniform branches).
    if (g == 1) {
        red[(rp * 2 + 0) * 64 + col] = acc0;
        red[(rp * 2 + 1) * 64 + col] = acc1;
    }
    __syncthreads();
    if (g == 0) {
        acc0 += red[(rp * 2 + 0) * 64 + col];
        acc1 += red[(rp * 2 + 1) * 64 + col];
        float* op = out + (((size_t)b * F_ + f) * H_ + gy0) * W_ + col;
        op[0]  = acc0;
        op[W_] = acc1;
    }
}

extern "C" void kernel_launch(void* const* d_in, const int* in_sizes, int n_in,
                              void* d_out, int out_size, void* d_ws, size_t ws_size,
                              hipStream_t stream) {
    const float* x      = (const float*)d_in[0];
    const float* nums   = (const float*)d_in[1];
    const float* denoms = (const float*)d_in[2];
    float* outp = (float*)d_out;
    dim3 grid(B_ * 16 * F_);   // 2048 blocks: (b, 4-row tile, f)
    ka_rconv_kernel<<<grid, 256, 0, stream>>>(x, nums, denoms, outp);
}

// Round 6
// 116.933 us; speedup vs baseline: 1.5831x; 1.5831x over previous
//
#include <hip/hip_runtime.h>

#define B_ 4
#define C_ 16
#define H_ 64
#define W_ 64
#define F_ 32

// 2 px/thread (vertical row pair) x 8 channels/thread (2-way channel split).
// Block 256 = 64 cols x {2 channel halves} x {2 row pairs}; grid 2048 blocks
// -> 8192 waves -> 8 waves/SIMD. NO min-waves launch_bounds clause: R5 proved
// capping VGPRs at 32 spills ~50 regs of state to scratch (FETCH_SIZE 247 MB).
// Instead the state is shrunk: row offsets/masks are wave-uniform (forced to
// SGPRs via readfirstlane), only column offsets + masks + xv live in VGPRs.
__global__ __launch_bounds__(256)
void ka_rconv_kernel(const float* __restrict__ xin,
                     const float* __restrict__ nums,
                     const float* __restrict__ denoms,
                     float* __restrict__ out) {
    __shared__ float red[2 * 2 * 64];   // [rp][row-in-pair][col]

    const int tid = threadIdx.x;
    const int col = tid & 63;          // lane = column -> coalesced
    const int g   = (tid >> 6) & 1;    // channel half (wave-uniform)
    const int rp  = tid >> 7;          // row pair (wave-uniform)

    int bid = blockIdx.x;
    const int f  = bid & 31;  bid >>= 5;
    const int t4 = bid & 15;  bid >>= 4;   // 4-row tile
    const int b  = bid;
    const int gy0 = t4 * 4 + rp * 2;       // first of this thread's 2 rows

    // Wave-uniform row state -> SGPRs (readfirstlane), per-lane column state -> 3 VGPRs.
    int   rowoff[4];    // scalar
    float mrow[4];      // scalar 0/1
    #pragma unroll
    for (int a = 0; a < 4; ++a) {
        const int gy  = gy0 + a - 1;
        const int gyc = min(max(gy, 0), H_ - 1);
        rowoff[a] = __builtin_amdgcn_readfirstlane(gyc * W_);
        mrow[a]   = ((gy >= 0) && (gy < H_)) ? 1.0f : 0.0f;
    }
    int   coloff[3];
    float msk[4][3];    // combined row*col 0/1 masks (computed once)
    #pragma unroll
    for (int j = 0; j < 3; ++j) {
        const int gx  = col + j - 1;
        const int gxc = min(max(gx, 0), W_ - 1);
        coloff[j] = gxc;
        const float mc = ((gx >= 0) && (gx < W_)) ? 1.0f : 0.0f;
        #pragma unroll
        for (int a = 0; a < 4; ++a) msk[a][j] = mc * mrow[a];
    }

    const int c0 = g * 8;
    const float* nbase = nums   + ((size_t)f * C_ + c0) * 54;   // uniform -> s_load
    const float* dbase = denoms + ((size_t)f * C_ + c0) * 36;
    const float* xb    = xin + ((size_t)b * C_ + c0) * (H_ * W_);

    float acc0 = 0.f, acc1 = 0.f;

    #pragma unroll 2
    for (int c = 0; c < 8; ++c) {
        const float* xc = xb + c * (H_ * W_);
        float xv[4][3];
        #pragma unroll
        for (int a = 0; a < 4; ++a) {
            const float* xr = xc + rowoff[a];   // scalar base + vector col offset
            #pragma unroll
            for (int j = 0; j < 3; ++j)
                xv[a][j] = xr[coloff[j]] * msk[a][j];
        }

        const float* np = nbase + c * 54;
        const float* dp = dbase + c * 36;
        #pragma unroll
        for (int a = 0; a < 3; ++a) {
            #pragma unroll
            for (int j = 0; j < 3; ++j) {
                const int t = a * 3 + j;
                const float n0 = np[t*6+0], n1 = np[t*6+1], n2 = np[t*6+2];
                const float n3 = np[t*6+3], n4 = np[t*6+4], n5 = np[t*6+5];
                const float d0 = dp[t*4+0], d1 = dp[t*4+1], d2 = dp[t*4+2], d3 = dp[t*4+3];

                const float x0 = xv[a][j];       // row gy0
                const float x1 = xv[a + 1][j];   // row gy0+1

                float P0 = fmaf(n5, x0, n4);
                float P1 = fmaf(n5, x1, n4);
                P0 = fmaf(P0, x0, n3);  P1 = fmaf(P1, x1, n3);
                P0 = fmaf(P0, x0, n2);  P1 = fmaf(P1, x1, n2);
                P0 = fmaf(P0, x0, n1);  P1 = fmaf(P1, x1, n1);
                P0 = fmaf(P0, x0, n0);  P1 = fmaf(P1, x1, n0);

                float Q0 = fmaf(d3, x0, d2);
                float Q1 = fmaf(d3, x1, d2);
                Q0 = fmaf(Q0, x0, d1);  Q1 = fmaf(Q1, x1, d1);
                Q0 = fmaf(Q0, x0, d0);  Q1 = fmaf(Q1, x1, d0);
                Q0 *= x0;               Q1 *= x1;
                Q0 = 1.0f + fabsf(Q0);  Q1 = 1.0f + fabsf(Q1);

                acc0 = fmaf(P0, __builtin_amdgcn_rcpf(Q0), acc0);
                acc1 = fmaf(P1, __builtin_amdgcn_rcpf(Q1), acc1);
            }
        }
    }

    // 2-way channel reduction through LDS (wave-uniform branches).
    if (g == 1) {
        red[(rp * 2 + 0) * 64 + col] = acc0;
        red[(rp * 2 + 1) * 64 + col] = acc1;
    }
    __syncthreads();
    if (g == 0) {
        acc0 += red[(rp * 2 + 0) * 64 + col];
        acc1 += red[(rp * 2 + 1) * 64 + col];
        float* op = out + (((size_t)b * F_ + f) * H_ + gy0) * W_ + col;
        op[0]  = acc0;
        op[W_] = acc1;
    }
}

extern "C" void kernel_launch(void* const* d_in, const int* in_sizes, int n_in,
                              void* d_out, int out_size, void* d_ws, size_t ws_size,
                              hipStream_t stream) {
    const float* x      = (const float*)d_in[0];
    const float* nums   = (const float*)d_in[1];
    const float* denoms = (const float*)d_in[2];
    float* outp = (float*)d_out;
    dim3 grid(B_ * 16 * F_);   // 2048 blocks: (b, 4-row tile, f)
    ka_rconv_kernel<<<grid, 256, 0, stream>>>(x, nums, denoms, outp);
}

// Round 7
// 112.100 us; speedup vs baseline: 1.6513x; 1.0431x over previous
//
#include <hip/hip_runtime.h>

#define B_ 4
#define C_ 16
#define H_ 64
#define W_ 64
#define F_ 32

// 2 px/thread (vertical row pair) x 8 channels/thread (2-way channel split).
// Block 256 = 64 cols x {2 channel halves} x {2 row pairs}; grid 2048 blocks
// -> 8192 waves -> 8 waves/SIMD.
// R5 lesson: never cap VGPRs below live state (spills -> 247 MB HBM).
// R6 lesson: VGPR=68 crosses the 64-reg occupancy cliff (unroll-2 added +24
// regs) -> 28% occupancy. This round: identical structure, NO channel unroll,
// keeping live state ~45 VGPRs so 8 waves/SIMD are legitimately resident.
__global__ __launch_bounds__(256)
void ka_rconv_kernel(const float* __restrict__ xin,
                     const float* __restrict__ nums,
                     const float* __restrict__ denoms,
                     float* __restrict__ out) {
    __shared__ float red[2 * 2 * 64];   // [rp][row-in-pair][col]

    const int tid = threadIdx.x;
    const int col = tid & 63;          // lane = column -> coalesced
    const int g   = (tid >> 6) & 1;    // channel half (wave-uniform)
    const int rp  = tid >> 7;          // row pair (wave-uniform)

    int bid = blockIdx.x;
    const int f  = bid & 31;  bid >>= 5;
    const int t4 = bid & 15;  bid >>= 4;   // 4-row tile
    const int b  = bid;
    const int gy0 = t4 * 4 + rp * 2;       // first of this thread's 2 rows

    // Wave-uniform row offsets -> SGPRs; per-lane column offsets -> 3 VGPRs.
    int   rowoff[4];
    float mrow[4];
    #pragma unroll
    for (int a = 0; a < 4; ++a) {
        const int gy  = gy0 + a - 1;
        const int gyc = min(max(gy, 0), H_ - 1);
        rowoff[a] = __builtin_amdgcn_readfirstlane(gyc * W_);
        mrow[a]   = ((gy >= 0) && (gy < H_)) ? 1.0f : 0.0f;
    }
    int   coloff[3];
    float msk[4][3];    // combined row*col 0/1 masks
    #pragma unroll
    for (int j = 0; j < 3; ++j) {
        const int gx  = col + j - 1;
        const int gxc = min(max(gx, 0), W_ - 1);
        coloff[j] = gxc;
        const float mc = ((gx >= 0) && (gx < W_)) ? 1.0f : 0.0f;
        #pragma unroll
        for (int a = 0; a < 4; ++a) msk[a][j] = mc * mrow[a];
    }

    const int c0 = g * 8;
    const float* nbase = nums   + ((size_t)f * C_ + c0) * 54;   // uniform -> s_load
    const float* dbase = denoms + ((size_t)f * C_ + c0) * 36;
    const float* xb    = xin + ((size_t)b * C_ + c0) * (H_ * W_);

    float acc0 = 0.f, acc1 = 0.f;

    for (int c = 0; c < 8; ++c) {          // NOT unrolled: keeps xv live-set single
        const float* xc = xb + c * (H_ * W_);
        float xv[4][3];
        #pragma unroll
        for (int a = 0; a < 4; ++a) {
            const float* xr = xc + rowoff[a];   // scalar base + vector col offset
            #pragma unroll
            for (int j = 0; j < 3; ++j)
                xv[a][j] = xr[coloff[j]] * msk[a][j];
        }

        const float* np = nbase + c * 54;
        const float* dp = dbase + c * 36;
        #pragma unroll
        for (int a = 0; a < 3; ++a) {
            #pragma unroll
            for (int j = 0; j < 3; ++j) {
                const int t = a * 3 + j;
                const float n0 = np[t*6+0], n1 = np[t*6+1], n2 = np[t*6+2];
                const float n3 = np[t*6+3], n4 = np[t*6+4], n5 = np[t*6+5];
                const float d0 = dp[t*4+0], d1 = dp[t*4+1], d2 = dp[t*4+2], d3 = dp[t*4+3];

                const float x0 = xv[a][j];       // row gy0
                const float x1 = xv[a + 1][j];   // row gy0+1

                float P0 = fmaf(n5, x0, n4);
                float P1 = fmaf(n5, x1, n4);
                P0 = fmaf(P0, x0, n3);  P1 = fmaf(P1, x1, n3);
                P0 = fmaf(P0, x0, n2);  P1 = fmaf(P1, x1, n2);
                P0 = fmaf(P0, x0, n1);  P1 = fmaf(P1, x1, n1);
                P0 = fmaf(P0, x0, n0);  P1 = fmaf(P1, x1, n0);

                float Q0 = fmaf(d3, x0, d2);
                float Q1 = fmaf(d3, x1, d2);
                Q0 = fmaf(Q0, x0, d1);  Q1 = fmaf(Q1, x1, d1);
                Q0 = fmaf(Q0, x0, d0);  Q1 = fmaf(Q1, x1, d0);
                Q0 *= x0;               Q1 *= x1;
                Q0 = 1.0f + fabsf(Q0);  Q1 = 1.0f + fabsf(Q1);

                acc0 = fmaf(P0, __builtin_amdgcn_rcpf(Q0), acc0);
                acc1 = fmaf(P1, __builtin_amdgcn_rcpf(Q1), acc1);
            }
        }
    }

    // 2-way channel reduction through LDS (wave-uniform branches).
    if (g == 1) {
        red[(rp * 2 + 0) * 64 + col] = acc0;
        red[(rp * 2 + 1) * 64 + col] = acc1;
    }
    __syncthreads();
    if (g == 0) {
        acc0 += red[(rp * 2 + 0) * 64 + col];
        acc1 += red[(rp * 2 + 1) * 64 + col];
        float* op = out + (((size_t)b * F_ + f) * H_ + gy0) * W_ + col;
        op[0]  = acc0;
        op[W_] = acc1;
    }
}

extern "C" void kernel_launch(void* const* d_in, const int* in_sizes, int n_in,
                              void* d_out, int out_size, void* d_ws, size_t ws_size,
                              hipStream_t stream) {
    const float* x      = (const float*)d_in[0];
    const float* nums   = (const float*)d_in[1];
    const float* denoms = (const float*)d_in[2];
    float* outp = (float*)d_out;
    dim3 grid(B_ * 16 * F_);   // 2048 blocks: (b, 4-row tile, f)
    ka_rconv_kernel<<<grid, 256, 0, stream>>>(x, nums, denoms, outp);
}

// Round 8
// 84.839 us; speedup vs baseline: 2.1820x; 1.3213x over previous
//
#include <hip/hip_runtime.h>

#define B_ 4
#define C_ 16
#define H_ 64
#define W_ 64
#define F_ 32

// 2 px/thread (vertical row pair) x 8 channels/thread (2-way channel split).
// Block 256 = 64 cols x {2 channel halves} x {2 row pairs}; grid 2048 blocks
// -> 8192 waves -> 8 waves/SIMD.
// R5: capping VGPRs spills (FETCH 247 MB). R6: VGPR=68 crosses the 64-reg
// occupancy cliff. R7: SGPR=32 exposed that `g`-dependent coeff bases are not
// provably wave-uniform -> compiler demoted coefficient s_loads to per-lane
// VMEM loads (R4 had SGPR=112 and was fastest). This round: readfirstlane(c0)
// restores compile-time uniformity -> batched s_load coefficients.
__global__ __launch_bounds__(256)
void ka_rconv_kernel(const float* __restrict__ xin,
                     const float* __restrict__ nums,
                     const float* __restrict__ denoms,
                     float* __restrict__ out) {
    __shared__ float red[2 * 2 * 64];   // [rp][row-in-pair][col]

    const int tid = threadIdx.x;
    const int col = tid & 63;          // lane = column -> coalesced
    const int g   = (tid >> 6) & 1;    // channel half (wave-uniform at runtime)
    const int rp  = tid >> 7;          // row pair (wave-uniform at runtime)

    int bid = blockIdx.x;
    const int f  = bid & 31;  bid >>= 5;
    const int t4 = bid & 15;  bid >>= 4;   // 4-row tile
    const int b  = bid;
    const int gy0 = t4 * 4 + rp * 2;       // first of this thread's 2 rows

    // Force wave-uniform values into the scalar domain so the compiler can
    // prove uniformity -> s_load for coefficients, scalar bases for x rows.
    const int c0 = __builtin_amdgcn_readfirstlane(g * 8);

    int   rowoff[4];
    float mrow[4];
    #pragma unroll
    for (int a = 0; a < 4; ++a) {
        const int gy  = gy0 + a - 1;
        const int gyc = min(max(gy, 0), H_ - 1);
        rowoff[a] = __builtin_amdgcn_readfirstlane(gyc * W_);
        mrow[a]   = ((gy >= 0) && (gy < H_)) ? 1.0f : 0.0f;
    }
    int   coloff[3];
    float msk[4][3];    // combined row*col 0/1 masks
    #pragma unroll
    for (int j = 0; j < 3; ++j) {
        const int gx  = col + j - 1;
        const int gxc = min(max(gx, 0), W_ - 1);
        coloff[j] = gxc;
        const float mc = ((gx >= 0) && (gx < W_)) ? 1.0f : 0.0f;
        #pragma unroll
        for (int a = 0; a < 4; ++a) msk[a][j] = mc * mrow[a];
    }

    const float* nbase = nums   + ((size_t)f * C_ + c0) * 54;   // uniform -> s_load
    const float* dbase = denoms + ((size_t)f * C_ + c0) * 36;
    const float* xb    = xin + ((size_t)b * C_ + c0) * (H_ * W_);

    float acc0 = 0.f, acc1 = 0.f;

    for (int c = 0; c < 8; ++c) {          // not unrolled: keeps xv live-set single
        const float* xc = xb + c * (H_ * W_);
        float xv[4][3];
        #pragma unroll
        for (int a = 0; a < 4; ++a) {
            const float* xr = xc + rowoff[a];   // scalar base + vector col offset
            #pragma unroll
            for (int j = 0; j < 3; ++j)
                xv[a][j] = xr[coloff[j]] * msk[a][j];
        }

        const float* np = nbase + c * 54;
        const float* dp = dbase + c * 36;
        #pragma unroll
        for (int a = 0; a < 3; ++a) {
            #pragma unroll
            for (int j = 0; j < 3; ++j) {
                const int t = a * 3 + j;
                const float n0 = np[t*6+0], n1 = np[t*6+1], n2 = np[t*6+2];
                const float n3 = np[t*6+3], n4 = np[t*6+4], n5 = np[t*6+5];
                const float d0 = dp[t*4+0], d1 = dp[t*4+1], d2 = dp[t*4+2], d3 = dp[t*4+3];

                const float x0 = xv[a][j];       // row gy0
                const float x1 = xv[a + 1][j];   // row gy0+1

                float P0 = fmaf(n5, x0, n4);
                float P1 = fmaf(n5, x1, n4);
                P0 = fmaf(P0, x0, n3);  P1 = fmaf(P1, x1, n3);
                P0 = fmaf(P0, x0, n2);  P1 = fmaf(P1, x1, n2);
                P0 = fmaf(P0, x0, n1);  P1 = fmaf(P1, x1, n1);
                P0 = fmaf(P0, x0, n0);  P1 = fmaf(P1, x1, n0);

                float Q0 = fmaf(d3, x0, d2);
                float Q1 = fmaf(d3, x1, d2);
                Q0 = fmaf(Q0, x0, d1);  Q1 = fmaf(Q1, x1, d1);
                Q0 = fmaf(Q0, x0, d0);  Q1 = fmaf(Q1, x1, d0);
                Q0 *= x0;               Q1 *= x1;
                Q0 = 1.0f + fabsf(Q0);  Q1 = 1.0f + fabsf(Q1);

                acc0 = fmaf(P0, __builtin_amdgcn_rcpf(Q0), acc0);
                acc1 = fmaf(P1, __builtin_amdgcn_rcpf(Q1), acc1);
            }
        }
    }

    // 2-way channel reduction through LDS (wave-uniform branches).
    if (g == 1) {
        red[(rp * 2 + 0) * 64 + col] = acc0;
        red[(rp * 2 + 1) * 64 + col] = acc1;
    }
    __syncthreads();
    if (g == 0) {
        acc0 += red[(rp * 2 + 0) * 64 + col];
        acc1 += red[(rp * 2 + 1) * 64 + col];
        float* op = out + (((size_t)b * F_ + f) * H_ + gy0) * W_ + col;
        op[0]  = acc0;
        op[W_] = acc1;
    }
}

extern "C" void kernel_launch(void* const* d_in, const int* in_sizes, int n_in,
                              void* d_out, int out_size, void* d_ws, size_t ws_size,
                              hipStream_t stream) {
    const float* x      = (const float*)d_in[0];
    const float* nums   = (const float*)d_in[1];
    const float* denoms = (const float*)d_in[2];
    float* outp = (float*)d_out;
    dim3 grid(B_ * 16 * F_);   // 2048 blocks: (b, 4-row tile, f)
    ka_rconv_kernel<<<grid, 256, 0, stream>>>(x, nums, denoms, outp);
}

// Round 9
// 84.251 us; speedup vs baseline: 2.1972x; 1.0070x over previous
//
#include <hip/hip_runtime.h>

#define B_ 4
#define C_ 16
#define H_ 64
#define W_ 64
#define F_ 32
#define S_ 66                   // padded row stride
#define CH_ (S_ * S_)           // padded channel size = 4356 floats
#define NPAD_ (B_ * C_ * CH_)   // 278784 floats = 1.12 MB (fits d_ws)

// Prolog: physical zero-padding of x into d_ws as (B,C,66,66).
// Runs every launch (d_ws is re-poisoned to 0xAA before each timed call).
__global__ __launch_bounds__(256)
void pad_kernel(const float* __restrict__ x, float* __restrict__ xp) {
    const int i  = blockIdx.x * 256 + threadIdx.x;   // grid sized exactly NPAD_
    const int cc = i % S_;
    const int t  = i / S_;
    const int r  = t % S_;
    const int bc = t / S_;
    float v = 0.f;
    if (r >= 1 && r <= H_ && cc >= 1 && cc <= W_)
        v = x[(size_t)bc * (H_ * W_) + (r - 1) * W_ + (cc - 1)];
    xp[i] = v;
}

// Main: 2 px/thread (row pair) x 8 ch/thread (2-way split), 8192 waves = 8/SIMD.
// No masks/clamps (physical padding) -> 4x dwordx3 loads/channel + explicit
// 2-deep channel double-buffer in the freed registers.
// History: R5 vgpr-cap spilled (247MB); R6 vgpr=68 crossed 64-cliff; R7
// sgpr=32 showed coeff bases demoted off the scalar path; R8 readfirstlane
// fixed that (35us). This round removes mask overhead + adds prefetch.
__global__ __launch_bounds__(256)
void ka_rconv_kernel(const float* __restrict__ xp,
                     const float* __restrict__ nums,
                     const float* __restrict__ denoms,
                     float* __restrict__ out) {
    __shared__ float red[2 * 2 * 64];

    const int tid = threadIdx.x;
    const int col = tid & 63;          // lane = column -> coalesced
    const int g   = (tid >> 6) & 1;    // channel half (wave-uniform)
    const int rp  = tid >> 7;          // row pair (wave-uniform)

    int bid = blockIdx.x;
    const int f  = bid & 31;  bid >>= 5;
    const int t4 = bid & 15;  bid >>= 4;
    const int b  = bid;
    const int gy0 = t4 * 4 + rp * 2;

    const int c0 = __builtin_amdgcn_readfirstlane(g * 8);   // keep coeff bases scalar

    const float* nbase = nums   + ((size_t)f * C_ + c0) * 54;   // -> batched s_load
    const float* dbase = denoms + ((size_t)f * C_ + c0) * 36;
    // input row gy0-1 => padded row gy0; input col col-1 => padded col col.
    const float* xb = xp + ((size_t)(b * C_ + c0)) * CH_ + gy0 * S_ + col;

    float acc0 = 0.f, acc1 = 0.f;
    float3 A[4], Bv[4];

    auto loadrows = [&](float3* dst, const float* p) {
        #pragma unroll
        for (int a = 0; a < 4; ++a)
            dst[a] = *(const float3*)(p + a * S_);   // global_load_dwordx3
    };

    auto evalch = [&](const float3* rv, int c) {
        const float* np = nbase + c * 54;
        const float* dp = dbase + c * 36;
        #pragma unroll
        for (int a = 0; a < 3; ++a) {
            #pragma unroll
            for (int j = 0; j < 3; ++j) {
                const int t = a * 3 + j;
                const float x0 = (j == 0) ? rv[a].x     : (j == 1) ? rv[a].y     : rv[a].z;
                const float x1 = (j == 0) ? rv[a + 1].x : (j == 1) ? rv[a + 1].y : rv[a + 1].z;
                const float n0 = np[t*6+0], n1 = np[t*6+1], n2 = np[t*6+2];
                const float n3 = np[t*6+3], n4 = np[t*6+4], n5 = np[t*6+5];
                const float d0 = dp[t*4+0], d1 = dp[t*4+1], d2 = dp[t*4+2], d3 = dp[t*4+3];

                float P0 = fmaf(n5, x0, n4), P1 = fmaf(n5, x1, n4);
                P0 = fmaf(P0, x0, n3);  P1 = fmaf(P1, x1, n3);
                P0 = fmaf(P0, x0, n2);  P1 = fmaf(P1, x1, n2);
                P0 = fmaf(P0, x0, n1);  P1 = fmaf(P1, x1, n1);
                P0 = fmaf(P0, x0, n0);  P1 = fmaf(P1, x1, n0);

                float Q0 = fmaf(d3, x0, d2), Q1 = fmaf(d3, x1, d2);
                Q0 = fmaf(Q0, x0, d1);  Q1 = fmaf(Q1, x1, d1);
                Q0 = fmaf(Q0, x0, d0);  Q1 = fmaf(Q1, x1, d0);
                Q0 *= x0;               Q1 *= x1;
                Q0 = 1.0f + fabsf(Q0);  Q1 = 1.0f + fabsf(Q1);

                acc0 = fmaf(P0, __builtin_amdgcn_rcpf(Q0), acc0);
                acc1 = fmaf(P1, __builtin_amdgcn_rcpf(Q1), acc1);
            }
        }
    };

    // 2-deep software pipeline over channels (no register copies: A/B alternate).
    loadrows(A, xb);
    const float* pa = xb;
    const float* pb = xb + CH_;
    #pragma unroll 1
    for (int c = 0; c < 8; c += 2) {
        loadrows(Bv, pb);                       // prefetch channel c+1
        evalch(A, c);
        pa += 2 * CH_;
        if (c + 2 < 8) loadrows(A, pa);         // prefetch channel c+2
        evalch(Bv, c + 1);
        pb += 2 * CH_;
    }

    // 2-way channel reduction through LDS (wave-uniform branches).
    if (g == 1) {
        red[(rp * 2 + 0) * 64 + col] = acc0;
        red[(rp * 2 + 1) * 64 + col] = acc1;
    }
    __syncthreads();
    if (g == 0) {
        acc0 += red[(rp * 2 + 0) * 64 + col];
        acc1 += red[(rp * 2 + 1) * 64 + col];
        float* op = out + (((size_t)b * F_ + f) * H_ + gy0) * W_ + col;
        op[0]  = acc0;
        op[W_] = acc1;
    }
}

extern "C" void kernel_launch(void* const* d_in, const int* in_sizes, int n_in,
                              void* d_out, int out_size, void* d_ws, size_t ws_size,
                              hipStream_t stream) {
    const float* x      = (const float*)d_in[0];
    const float* nums   = (const float*)d_in[1];
    const float* denoms = (const float*)d_in[2];
    float* outp = (float*)d_out;
    float* xpad = (float*)d_ws;                      // needs 1.12 MB of d_ws

    pad_kernel<<<NPAD_ / 256, 256, 0, stream>>>(x, xpad);
    dim3 grid(B_ * 16 * F_);                         // 2048 blocks: (b, 4-row tile, f)
    ka_rconv_kernel<<<grid, 256, 0, stream>>>(xpad, nums, denoms, outp);
}

// Round 10
// 83.202 us; speedup vs baseline: 2.2249x; 1.0126x over previous
//
#include <hip/hip_runtime.h>

#define B_ 4
#define C_ 16
#define H_ 64
#define W_ 64
#define F_ 32
#define S_ 66                   // padded row stride
#define CH_ (S_ * S_)           // padded channel = 4356 floats
#define NPAD_ (B_ * C_ * CH_)   // 1.12 MB in d_ws
#define CST 12                  // LDS floats per (c,tap): n0..n5,d0..d3,pad2 (48B, 16B-aligned)

// Prolog: physical zero-pad of x into d_ws as (B,C,66,66).
__global__ __launch_bounds__(256)
void pad_kernel(const float* __restrict__ x, float* __restrict__ xp) {
    const int i  = blockIdx.x * 256 + threadIdx.x;
    const int cc = i % S_;
    const int t  = i / S_;
    const int r  = t % S_;
    const int bc = t / S_;
    float v = 0.f;
    if (r >= 1 && r <= H_ && cc >= 1 && cc <= W_)
        v = x[(size_t)bc * (H_ * W_) + (r - 1) * W_ + (cc - 1)];
    xp[i] = v;
}

// 2 px/thread x 8 ch/thread, 8192 waves = 8/SIMD.
// R8 showed per-channel s_load coeff round-trips are the stall (SGPR budget
// can't double-buffer 90 dwords); R9 showed x-prefetch is NOT the stall.
// This round: coefficients staged ONCE per block into LDS (shared by all 8
// waves, broadcast ds_read_b128 with fine-grained lgkmcnt, separate pipe).
__global__ __launch_bounds__(256)
void ka_rconv_kernel(const float* __restrict__ xp,
                     const float* __restrict__ nums,
                     const float* __restrict__ denoms,
                     float* __restrict__ out) {
    __shared__ alignas(16) float sc[C_ * 9 * CST];   // 6.9 KB coeffs for this f
    __shared__ float red[2 * 2 * 64];

    const int tid = threadIdx.x;
    const int col = tid & 63;          // lane = column -> coalesced
    const int g   = (tid >> 6) & 1;    // channel half (wave-uniform)
    const int rp  = tid >> 7;          // row pair (wave-uniform)

    int bid = blockIdx.x;
    const int f  = bid & 31;  bid >>= 5;
    const int t4 = bid & 15;  bid >>= 4;
    const int b  = bid;
    const int gy0 = t4 * 4 + rp * 2;

    // ---- stage this f's coefficients into LDS (coalesced, once per block) ----
    {
        const float* np = nums + (size_t)f * (C_ * 54);
        for (int i = tid; i < C_ * 54; i += 256) {
            int e = i / 6, j = i - e * 6;
            sc[e * CST + j] = np[i];
        }
        const float* dp = denoms + (size_t)f * (C_ * 36);
        for (int i = tid; i < C_ * 36; i += 256) {
            int e = i / 4, j = i - e * 4;
            sc[e * CST + 6 + j] = dp[i];
        }
    }
    __syncthreads();

    const int chb = g * 8;
    const float* xb = xp + ((size_t)(b * C_ + chb)) * CH_ + gy0 * S_ + col;
    const float* cp = sc + chb * (9 * CST);

    float acc0 = 0.f, acc1 = 0.f;

    for (int c = 0; c < 8; ++c) {
        const float* xr = xb + c * CH_;
        float3 rv[4];
        #pragma unroll
        for (int a = 0; a < 4; ++a)
            rv[a] = *(const float3*)(xr + a * S_);   // global_load_dwordx3

        const float* ce = cp + c * (9 * CST);
        #pragma unroll
        for (int t = 0; t < 9; ++t) {
            // broadcast LDS reads: all lanes same address -> conflict-free
            const float4 k0 = *(const float4*)(ce + t * CST);      // n0 n1 n2 n3
            const float4 k1 = *(const float4*)(ce + t * CST + 4);  // n4 n5 d0 d1
            const float2 k2 = *(const float2*)(ce + t * CST + 8);  // d2 d3
            const int a = t / 3, j = t % 3;
            const float x0 = (j == 0) ? rv[a].x     : (j == 1) ? rv[a].y     : rv[a].z;
            const float x1 = (j == 0) ? rv[a + 1].x : (j == 1) ? rv[a + 1].y : rv[a + 1].z;

            float P0 = fmaf(k1.y, x0, k1.x), P1 = fmaf(k1.y, x1, k1.x);
            P0 = fmaf(P0, x0, k0.w);  P1 = fmaf(P1, x1, k0.w);
            P0 = fmaf(P0, x0, k0.z);  P1 = fmaf(P1, x1, k0.z);
            P0 = fmaf(P0, x0, k0.y);  P1 = fmaf(P1, x1, k0.y);
            P0 = fmaf(P0, x0, k0.x);  P1 = fmaf(P1, x1, k0.x);

            float Q0 = fmaf(k2.y, x0, k2.x), Q1 = fmaf(k2.y, x1, k2.x);
            Q0 = fmaf(Q0, x0, k1.w);  Q1 = fmaf(Q1, x1, k1.w);
            Q0 = fmaf(Q0, x0, k1.z);  Q1 = fmaf(Q1, x1, k1.z);
            Q0 *= x0;                 Q1 *= x1;
            Q0 = 1.0f + fabsf(Q0);    Q1 = 1.0f + fabsf(Q1);

            acc0 = fmaf(P0, __builtin_amdgcn_rcpf(Q0), acc0);
            acc1 = fmaf(P1, __builtin_amdgcn_rcpf(Q1), acc1);
        }
    }

    // 2-way channel reduction through LDS (wave-uniform branches).
    if (g == 1) {
        red[(rp * 2 + 0) * 64 + col] = acc0;
        red[(rp * 2 + 1) * 64 + col] = acc1;
    }
    __syncthreads();
    if (g == 0) {
        acc0 += red[(rp * 2 + 0) * 64 + col];
        acc1 += red[(rp * 2 + 1) * 64 + col];
        float* op = out + (((size_t)b * F_ + f) * H_ + gy0) * W_ + col;
        op[0]  = acc0;
        op[W_] = acc1;
    }
}

extern "C" void kernel_launch(void* const* d_in, const int* in_sizes, int n_in,
                              void* d_out, int out_size, void* d_ws, size_t ws_size,
                              hipStream_t stream) {
    const float* x      = (const float*)d_in[0];
    const float* nums   = (const float*)d_in[1];
    const float* denoms = (const float*)d_in[2];
    float* outp = (float*)d_out;
    float* xpad = (float*)d_ws;

    pad_kernel<<<NPAD_ / 256, 256, 0, stream>>>(x, xpad);
    dim3 grid(B_ * 16 * F_);   // 2048 blocks: (b, 4-row tile, f)
    ka_rconv_kernel<<<grid, 256, 0, stream>>>(xpad, nums, denoms, outp);
}